// Round 11
// baseline (90.497 us; speedup 1.0000x reference)
//
#include <hip/hip_runtime.h>

#define NN 2048
#define KK 512

typedef __attribute__((ext_vector_type(8))) short bf16x8;
typedef __attribute__((ext_vector_type(8))) _Float16 f16x8;
typedef __attribute__((ext_vector_type(4))) float f32x4;

__device__ inline ushort f2bf(float x) {  // RNE f32->bf16
  union { float f; unsigned u; } v; v.f = x;
  unsigned r = v.u + 0x7fffu + ((v.u >> 16) & 1u);
  return (ushort)(r >> 16);
}

// -------- K0: W -> WT_hi/WT_lo (bf16 split, [n][k] layout). grid 32 --------
__global__ __launch_bounds__(256) void k_wprep(
    const float* __restrict__ W, ushort* __restrict__ wthi,
    ushort* __restrict__ wtlo) {
  __shared__ float ts[64][65];
  const int t = threadIdx.x;
  const int kb = (blockIdx.x >> 2) * 64;
  const int nb = (blockIdx.x & 3) * 64;
  const int r = t >> 6, c = t & 63;
#pragma unroll
  for (int p = 0; p < 16; ++p)
    ts[p * 4 + r][c] = W[(size_t)(kb + p * 4 + r) * 256 + nb + c];
  __syncthreads();
#pragma unroll
  for (int p = 0; p < 16; ++p) {
    int n = p * 4 + r;
    int k = c;
    float v = ts[k][n];
    union { float f; unsigned u; } q; q.f = v;
    ushort hi = (ushort)(q.u >> 16);
    union { float f; unsigned u; } hf; hf.u = q.u & 0xffff0000u;
    ushort lo = f2bf(v - hf.f);
    size_t off = (size_t)(nb + n) * KK + kb + k;
    wthi[off] = hi;
    wtlo[off] = lo;
  }
}

// -------- K1: g = h@W via split-bf16 MFMA. grid 256 (8 rows/block) ---------
// A-tile rows 8..15 duplicate 0..7 (discarded); only kg<2 D-rows written.
__global__ __launch_bounds__(256) void k_gemm(
    const float* __restrict__ hin, const ushort* __restrict__ wthi,
    const ushort* __restrict__ wtlo, const float* __restrict__ aw,
    ushort* __restrict__ gTb,
    float* __restrict__ Eel, float* __restrict__ Fel,
    float* __restrict__ Eer_jh, float* __restrict__ Fer_jh,
    float* __restrict__ Eer_hj, float* __restrict__ Fer_hj) {
  __shared__ float hs[8][516];
  const int tid = threadIdx.x;
  const int i0 = blockIdx.x * 8;
#pragma unroll
  for (int p = 0; p < 4; ++p) {
    int g4 = tid + p * 256;
    int row = g4 >> 7, col = (g4 & 127) << 2;
    *(float4*)&hs[row][col] = *(const float4*)(hin + (size_t)(i0 + row) * KK + col);
  }
  __syncthreads();

  const int h = tid >> 6;
  const int lane = tid & 63;
  const int il = lane & 15;
  const int kg = lane >> 4;

  f32x4 acc[4];
#pragma unroll
  for (int nt = 0; nt < 4; ++nt) acc[nt] = (f32x4){0.f, 0.f, 0.f, 0.f};

  const ushort* bh_base = wthi + (size_t)(h * 64 + il) * KK;
  const ushort* bl_base = wtlo + (size_t)(h * 64 + il) * KK;

#pragma unroll 4
  for (int ks = 0; ks < 16; ++ks) {
    const int ko = ks * 32 + kg * 8;
    float4 a01 = *(const float4*)&hs[il & 7][ko];
    float4 a23 = *(const float4*)&hs[il & 7][ko + 4];
    float av[8] = {a01.x, a01.y, a01.z, a01.w, a23.x, a23.y, a23.z, a23.w};
    union { unsigned u[4]; bf16x8 v; } Ah, Al;
#pragma unroll
    for (int p = 0; p < 4; ++p) {
      union { float f; unsigned u; } u0, u1;
      u0.f = av[2 * p]; u1.f = av[2 * p + 1];
      Ah.u[p] = (u0.u >> 16) | (u1.u & 0xffff0000u);
      union { float f; unsigned u; } h0, h1;
      h0.u = u0.u & 0xffff0000u;
      h1.u = u1.u & 0xffff0000u;
      union { float f; unsigned u; } r0, r1;
      r0.f = av[2 * p] - h0.f;
      r1.f = av[2 * p + 1] - h1.f;
      Al.u[p] = (r0.u >> 16) | (r1.u & 0xffff0000u);
    }
#pragma unroll
    for (int nt = 0; nt < 4; ++nt) {
      bf16x8 Bh = *(const bf16x8*)(bh_base + nt * 16 * KK + ko);
      bf16x8 Bl = *(const bf16x8*)(bl_base + nt * 16 * KK + ko);
      acc[nt] = __builtin_amdgcn_mfma_f32_16x16x32_bf16(Ah.v, Bh, acc[nt], 0, 0, 0);
      acc[nt] = __builtin_amdgcn_mfma_f32_16x16x32_bf16(Al.v, Bh, acc[nt], 0, 0, 0);
      acc[nt] = __builtin_amdgcn_mfma_f32_16x16x32_bf16(Ah.v, Bl, acc[nt], 0, 0, 0);
    }
  }

  // gTb write: layout [j/8][f][8] bf16; valid D-rows kg*4+q < 8 (kg<2)
  if (kg < 2) {
    const int jb = i0 >> 3;
    const int halfoff = kg * 4;
#pragma unroll
    for (int nt = 0; nt < 4; ++nt) {
      const int f = h * 64 + nt * 16 + il;
      unsigned w0 = (unsigned)f2bf(acc[nt][0]) | ((unsigned)f2bf(acc[nt][1]) << 16);
      unsigned w1 = (unsigned)f2bf(acc[nt][2]) | ((unsigned)f2bf(acc[nt][3]) << 16);
      uint2 pk = make_uint2(w0, w1);
      *(uint2*)(gTb + (size_t)jb * 2048 + f * 8 + halfoff) = pk;
    }
  }

  // el/er epilogue -> exp tables (reduction over il = 16 distinct f cols)
  float ela[4] = {0.f, 0.f, 0.f, 0.f}, era[4] = {0.f, 0.f, 0.f, 0.f};
#pragma unroll
  for (int nt = 0; nt < 4; ++nt) {
    float as = aw[nt * 16 + il];
    float ad = aw[64 + nt * 16 + il];
#pragma unroll
    for (int q = 0; q < 4; ++q) {
      ela[q] += acc[nt][q] * as;
      era[q] += acc[nt][q] * ad;
    }
  }
#pragma unroll
  for (int m = 1; m < 16; m <<= 1) {
#pragma unroll
    for (int q = 0; q < 4; ++q) {
      ela[q] += __shfl_xor(ela[q], m);
      era[q] += __shfl_xor(era[q], m);
    }
  }
  if (il == 0 && kg < 2) {
#pragma unroll
    for (int q = 0; q < 4; ++q) {
      const int row = i0 + kg * 4 + q;
      float eel = __expf(ela[q]);
      float fel = __expf(0.2f * ela[q]);
      float eer = __expf(era[q]);
      float fer = __expf(0.2f * era[q]);
      Eel[row * 4 + h] = eel;
      Fel[row * 4 + h] = fel;
      Eer_jh[row * 4 + h] = eer;
      Fer_jh[row * 4 + h] = fer;
      Eer_hj[h * NN + row] = eer;
      Fer_hj[h * NN + row] = fer;
    }
  }
}

// -------- K2: mega kernel. grid 512 (4 rows/block), block 512 (8 waves) ----
// Phase 1: wave = (row w&3, j-half w>>2): mask, exp(s)->f16 LDS, Z1/Z2 partial.
// Phase 2: wave = (head w&3, j-half w>>2): MFMA; A-rows duplicated 4x (il&3).
__global__ __launch_bounds__(512, 4) void k_mega(
    const float* __restrict__ adj, const float* __restrict__ s,
    const ushort* __restrict__ gTb,
    const float* __restrict__ Eel, const float* __restrict__ Fel,
    const float* __restrict__ Eer_jh, const float* __restrict__ Fer_jh,
    const float* __restrict__ Eer_hj, const float* __restrict__ Fer_hj,
    float* __restrict__ out) {
  __shared__ _Float16 es_s[4][2056];              // exp(s), masked (0 if !nb)
  __shared__ unsigned long long maskl[4][34];     // [row][j/64]
  __shared__ float zpart[8][5];                   // per-wave partials
  __shared__ float zrow[4][5];                    // [row][h]=1/Z1h, [4]=1/Z2
  __shared__ float z3L[2][4][4];                  // [jh][h][row]
  __shared__ _Float16 dacc[2][4][4][64];          // [jh][h][row][f]

  const int tid = threadIdx.x;
  const int w = tid >> 6;
  const int lane = tid & 63;
  const int i0 = blockIdx.x * 4;

  // ---------------- phase 1 ----------------
  {
    const int r1 = w & 3;
    const int jh1 = w >> 2;
    const int row = i0 + r1;
    const float* ap = adj + (size_t)row * NN + jh1 * 1024;
    const float* sp = s + (size_t)row * NN + jh1 * 1024;
    float4 e4 = *(const float4*)(Eel + row * 4);
    float4 f4 = *(const float4*)(Fel + row * 4);
    const float eel[4] = {e4.x, e4.y, e4.z, e4.w};
    const float fel[4] = {f4.x, f4.y, f4.z, f4.w};
    float z1[4] = {0.f, 0.f, 0.f, 0.f};
    float z2 = 0.f;
#pragma unroll 4
    for (int it = 0; it < 16; ++it) {
      const int j = it * 64 + lane;
      float a = ap[j];
      float sv = sp[j];
      bool nb = (a != 0.f);
      unsigned long long m = __ballot(nb);
      if (lane == 0) maskl[r1][jh1 * 16 + it] = m;
      float es = nb ? __expf(sv) : 0.f;
      es_s[r1][jh1 * 1024 + j] = (_Float16)es;
      z2 += es;
      const int jg = jh1 * 1024 + j;
      float4 eer4 = *(const float4*)(Eer_jh + jg * 4);
      float4 fer4 = *(const float4*)(Fer_jh + jg * 4);
      float ev[4] = {eer4.x, eer4.y, eer4.z, eer4.w};
      float fv[4] = {fer4.x, fer4.y, fer4.z, fer4.w};
#pragma unroll
      for (int h = 0; h < 4; ++h) {
        float E = fmaxf(eel[h] * ev[h], fel[h] * fv[h]);
        z1[h] += nb ? E : 0.f;
      }
    }
#pragma unroll
    for (int m = 1; m < 64; m <<= 1) {
      z2 += __shfl_xor(z2, m);
#pragma unroll
      for (int h = 0; h < 4; ++h) z1[h] += __shfl_xor(z1[h], m);
    }
    if (lane == 0) {
      zpart[w][0] = z1[0]; zpart[w][1] = z1[1];
      zpart[w][2] = z1[2]; zpart[w][3] = z1[3];
      zpart[w][4] = z2;
    }
  }
  __syncthreads();
  if (tid < 20) {
    const int r = tid / 5, c = tid % 5;
    zrow[r][c] = 1.f / (zpart[r][c] + zpart[4 + r][c]);
  }
  __syncthreads();

  // ---------------- phase 2: wave = (head, j-half) ----------------
  const int h = w & 3;
  const int jh = w >> 2;
  const int il = lane & 15;
  const int kg = lane >> 4;
  const int r = il & 3;             // real row (il>=4: duplicates, discarded)
  const int row = i0 + r;

  const float rz2 = zrow[r][4];
  const float eelz = Eel[row * 4 + h] * zrow[r][h];
  const float felz = Fel[row * 4 + h] * zrow[r][h];

  f32x4 acc[4];
#pragma unroll
  for (int nt = 0; nt < 4; ++nt) acc[nt] = (f32x4){0.f, 0.f, 0.f, 0.f};
  float z3 = 0.f;

  const ushort* bp = gTb + (size_t)(jh * 128 + kg) * 2048 + (h * 64 + il) * 8;
  const float* eerp = Eer_hj + h * NN + jh * 1024 + kg * 8;
  const float* ferp = Fer_hj + h * NN + jh * 1024 + kg * 8;

#pragma unroll 4
  for (int ks = 0; ks < 32; ++ks) {
    const ushort* bks = bp + (size_t)(ks * 4) * 2048;
    bf16x8 B0 = *(const bf16x8*)(bks);
    bf16x8 B1 = *(const bf16x8*)(bks + 128);
    bf16x8 B2 = *(const bf16x8*)(bks + 256);
    bf16x8 B3 = *(const bf16x8*)(bks + 384);

    unsigned long long mw = maskl[r][jh * 16 + (ks >> 1)];
    unsigned byte_ = (unsigned)(mw >> ((ks & 1) * 32 + kg * 8)) & 0xffu;
    const int jl = jh * 1024 + ks * 32 + kg * 8;
    const int go = ks * 32;

    f16x8 ev8 = *(const f16x8*)(&es_s[r][jl]);

    bf16x8 A;
#pragma unroll
    for (int e = 0; e < 8; ++e) {
      bool nb = (byte_ >> e) & 1u;
      float p = eelz * eerp[go + e];
      float q = felz * ferp[go + e];
      float tt = nb ? (fmaxf(p, q) + (float)ev8[e] * rz2) : 0.f;
      float c = __expf(tt);
      z3 += c;
      A[e] = (short)f2bf(c);
    }

    acc[0] = __builtin_amdgcn_mfma_f32_16x16x32_bf16(A, B0, acc[0], 0, 0, 0);
    acc[1] = __builtin_amdgcn_mfma_f32_16x16x32_bf16(A, B1, acc[1], 0, 0, 0);
    acc[2] = __builtin_amdgcn_mfma_f32_16x16x32_bf16(A, B2, acc[2], 0, 0, 0);
    acc[3] = __builtin_amdgcn_mfma_f32_16x16x32_bf16(A, B3, acc[3], 0, 0, 0);
  }

  // z3: lanes il,il+4,il+8,il+12 are duplicates -> reduce over kg only
  z3 += __shfl_xor(z3, 16);
  z3 += __shfl_xor(z3, 32);
  if (lane < 4) z3L[jh][h][lane] = z3;

  // D-tile: valid rows m = kg*4+q < 4 -> kg==0 lanes only
  if (kg == 0) {
#pragma unroll
    for (int nt = 0; nt < 4; ++nt)
#pragma unroll
      for (int q = 0; q < 4; ++q)
        dacc[jh][h][q][nt * 16 + il] = (_Float16)acc[nt][q];
  }
  __syncthreads();

  // ---------------- finalize ----------------
#pragma unroll
  for (int p = 0; p < 2; ++p) {
    const int v = tid + p * 512;
    const int rr = v >> 8;
    const int c = v & 255;
    const int hh = c >> 6;
    const int f = c & 63;
    float u = (float)dacc[0][hh][rr][f] + (float)dacc[1][hh][rr][f];
    float z = z3L[0][hh][rr] + z3L[1][hh][rr];
    out[(size_t)(i0 + rr) * 256 + c] = u / z;
  }
}

extern "C" void kernel_launch(void* const* d_in, const int* in_sizes, int n_in,
                              void* d_out, int out_size, void* d_ws, size_t ws_size,
                              hipStream_t stream) {
  const float* hin = (const float*)d_in[0];
  const float* adj = (const float*)d_in[1];
  const float* s = (const float*)d_in[2];
  const float* W = (const float*)d_in[3];
  const float* aw = (const float*)d_in[4];
  float* out = (float*)d_out;

  // Workspace (f32 slots) — audited, non-overlapping (1.7 MB total):
  //  Eel     [      0,    8192)
  //  Fel     [   8192,   16384)
  //  Eer_jh  [  16384,   24576)
  //  Fer_jh  [  24576,   32768)
  //  Eer_hj  [  32768,   40960)
  //  Fer_hj  [  40960,   49152)
  //  wthi    [  49152,  114688)   131072 ushort
  //  wtlo    [ 114688,  180224)   131072 ushort
  //  gTb     [ 180224,  442368)   524288 ushort
  float* ws = (float*)d_ws;
  float* Eel    = ws;
  float* Fel    = ws + 8192;
  float* Eer_jh = ws + 16384;
  float* Fer_jh = ws + 24576;
  float* Eer_hj = ws + 32768;
  float* Fer_hj = ws + 40960;
  ushort* wthi  = (ushort*)(ws + 49152);
  ushort* wtlo  = (ushort*)(ws + 114688);
  ushort* gTb   = (ushort*)(ws + 180224);

  k_wprep<<<32, 256, 0, stream>>>(W, wthi, wtlo);
  k_gemm<<<256, 256, 0, stream>>>(hin, wthi, wtlo, aw, gTb, Eel, Fel, Eer_jh, Fer_jh, Eer_hj, Fer_hj);
  k_mega<<<512, 512, 0, stream>>>(adj, s, gTb, Eel, Fel, Eer_jh, Fer_jh, Eer_hj, Fer_hj, out);
}

// Round 12
// 85.773 us; speedup vs baseline: 1.0551x; 1.0551x over previous
//
#include <hip/hip_runtime.h>

#define NN 2048
#define KK 512

typedef __attribute__((ext_vector_type(8))) short bf16x8;
typedef __attribute__((ext_vector_type(8))) _Float16 f16x8;
typedef __attribute__((ext_vector_type(4))) float f32x4;

__device__ inline ushort f2bf(float x) {  // RNE f32->bf16
  union { float f; unsigned u; } v; v.f = x;
  unsigned r = v.u + 0x7fffu + ((v.u >> 16) & 1u);
  return (ushort)(r >> 16);
}

// -------- K0: W -> WT_hi/WT_lo (bf16 split, [n][k] layout). grid 32 --------
__global__ __launch_bounds__(256) void k_wprep(
    const float* __restrict__ W, ushort* __restrict__ wthi,
    ushort* __restrict__ wtlo) {
  __shared__ float ts[64][65];
  const int t = threadIdx.x;
  const int kb = (blockIdx.x >> 2) * 64;
  const int nb = (blockIdx.x & 3) * 64;
  const int r = t >> 6, c = t & 63;
#pragma unroll
  for (int p = 0; p < 16; ++p)
    ts[p * 4 + r][c] = W[(size_t)(kb + p * 4 + r) * 256 + nb + c];
  __syncthreads();
#pragma unroll
  for (int p = 0; p < 16; ++p) {
    int n = p * 4 + r;
    int k = c;
    float v = ts[k][n];
    union { float f; unsigned u; } q; q.f = v;
    ushort hi = (ushort)(q.u >> 16);
    union { float f; unsigned u; } hf; hf.u = q.u & 0xffff0000u;
    ushort lo = f2bf(v - hf.f);
    size_t off = (size_t)(nb + n) * KK + kb + k;
    wthi[off] = hi;
    wtlo[off] = lo;
  }
}

// -------- K1: g = h@W via split-bf16 MFMA. grid 256 (8 rows/block) ---------
// A-tile rows 8..15 duplicate 0..7 (discarded); only kg<2 D-rows written.
__global__ __launch_bounds__(256) void k_gemm(
    const float* __restrict__ hin, const ushort* __restrict__ wthi,
    const ushort* __restrict__ wtlo, const float* __restrict__ aw,
    ushort* __restrict__ gTb,
    float* __restrict__ Eel, float* __restrict__ Fel,
    float* __restrict__ Eer_jh, float* __restrict__ Fer_jh,
    float2* __restrict__ EF_hj) {
  __shared__ float hs[8][516];
  const int tid = threadIdx.x;
  const int i0 = blockIdx.x * 8;
#pragma unroll
  for (int p = 0; p < 4; ++p) {
    int g4 = tid + p * 256;
    int row = g4 >> 7, col = (g4 & 127) << 2;
    *(float4*)&hs[row][col] = *(const float4*)(hin + (size_t)(i0 + row) * KK + col);
  }
  __syncthreads();

  const int h = tid >> 6;
  const int lane = tid & 63;
  const int il = lane & 15;
  const int kg = lane >> 4;

  f32x4 acc[4];
#pragma unroll
  for (int nt = 0; nt < 4; ++nt) acc[nt] = (f32x4){0.f, 0.f, 0.f, 0.f};

  const ushort* bh_base = wthi + (size_t)(h * 64 + il) * KK;
  const ushort* bl_base = wtlo + (size_t)(h * 64 + il) * KK;

#pragma unroll 4
  for (int ks = 0; ks < 16; ++ks) {
    const int ko = ks * 32 + kg * 8;
    float4 a01 = *(const float4*)&hs[il & 7][ko];
    float4 a23 = *(const float4*)&hs[il & 7][ko + 4];
    float av[8] = {a01.x, a01.y, a01.z, a01.w, a23.x, a23.y, a23.z, a23.w};
    union { unsigned u[4]; bf16x8 v; } Ah, Al;
#pragma unroll
    for (int p = 0; p < 4; ++p) {
      union { float f; unsigned u; } u0, u1;
      u0.f = av[2 * p]; u1.f = av[2 * p + 1];
      Ah.u[p] = (u0.u >> 16) | (u1.u & 0xffff0000u);
      union { float f; unsigned u; } h0, h1;
      h0.u = u0.u & 0xffff0000u;
      h1.u = u1.u & 0xffff0000u;
      union { float f; unsigned u; } r0, r1;
      r0.f = av[2 * p] - h0.f;
      r1.f = av[2 * p + 1] - h1.f;
      Al.u[p] = (r0.u >> 16) | (r1.u & 0xffff0000u);
    }
#pragma unroll
    for (int nt = 0; nt < 4; ++nt) {
      bf16x8 Bh = *(const bf16x8*)(bh_base + nt * 16 * KK + ko);
      bf16x8 Bl = *(const bf16x8*)(bl_base + nt * 16 * KK + ko);
      acc[nt] = __builtin_amdgcn_mfma_f32_16x16x32_bf16(Ah.v, Bh, acc[nt], 0, 0, 0);
      acc[nt] = __builtin_amdgcn_mfma_f32_16x16x32_bf16(Al.v, Bh, acc[nt], 0, 0, 0);
      acc[nt] = __builtin_amdgcn_mfma_f32_16x16x32_bf16(Ah.v, Bl, acc[nt], 0, 0, 0);
    }
  }

  // gTb write: layout [j/8][f][8] bf16; valid D-rows kg*4+q < 8 (kg<2)
  if (kg < 2) {
    const int jb = i0 >> 3;
    const int halfoff = kg * 4;
#pragma unroll
    for (int nt = 0; nt < 4; ++nt) {
      const int f = h * 64 + nt * 16 + il;
      unsigned w0 = (unsigned)f2bf(acc[nt][0]) | ((unsigned)f2bf(acc[nt][1]) << 16);
      unsigned w1 = (unsigned)f2bf(acc[nt][2]) | ((unsigned)f2bf(acc[nt][3]) << 16);
      uint2 pk = make_uint2(w0, w1);
      *(uint2*)(gTb + (size_t)jb * 2048 + f * 8 + halfoff) = pk;
    }
  }

  // el/er epilogue -> exp tables (reduction over il = 16 distinct f cols)
  float ela[4] = {0.f, 0.f, 0.f, 0.f}, era[4] = {0.f, 0.f, 0.f, 0.f};
#pragma unroll
  for (int nt = 0; nt < 4; ++nt) {
    float as = aw[nt * 16 + il];
    float ad = aw[64 + nt * 16 + il];
#pragma unroll
    for (int q = 0; q < 4; ++q) {
      ela[q] += acc[nt][q] * as;
      era[q] += acc[nt][q] * ad;
    }
  }
#pragma unroll
  for (int m = 1; m < 16; m <<= 1) {
#pragma unroll
    for (int q = 0; q < 4; ++q) {
      ela[q] += __shfl_xor(ela[q], m);
      era[q] += __shfl_xor(era[q], m);
    }
  }
  if (il == 0 && kg < 2) {
#pragma unroll
    for (int q = 0; q < 4; ++q) {
      const int row = i0 + kg * 4 + q;
      float eel = __expf(ela[q]);
      float fel = __expf(0.2f * ela[q]);
      float eer = __expf(era[q]);
      float fer = __expf(0.2f * era[q]);
      Eel[row * 4 + h] = eel;
      Fel[row * 4 + h] = fel;
      Eer_jh[row * 4 + h] = eer;
      Fer_jh[row * 4 + h] = fer;
      EF_hj[h * NN + row] = make_float2(eer, fer);
    }
  }
}

// -------- K3: Z1[h] + mask + Esb = f16(exp(s)*rZ2, masked). grid 2048 ------
// R8-proven version.
__global__ __launch_bounds__(256) void k_rowz(
    const float* __restrict__ adj, const float* __restrict__ s,
    const float* __restrict__ Eel, const float* __restrict__ Fel,
    const float* __restrict__ Eer_jh, const float* __restrict__ Fer_jh,
    float* __restrict__ rZ1, _Float16* __restrict__ Esb,
    unsigned long long* __restrict__ maskb) {
  __shared__ float es_row[2048];
  __shared__ float wr[4][5];
  const int row = blockIdx.x;
  const int tid = threadIdx.x;
  const int wq = tid >> 6;
  const int lane = tid & 63;

  float4 e4 = *(const float4*)(Eel + row * 4);
  float4 f4 = *(const float4*)(Fel + row * 4);
  const float eel[4] = {e4.x, e4.y, e4.z, e4.w};
  const float fel[4] = {f4.x, f4.y, f4.z, f4.w};

  float z1[4] = {0.f, 0.f, 0.f, 0.f};
  float z2 = 0.f;

  const float* ap = adj + (size_t)row * NN + wq * 512;
  const float* sp = s + (size_t)row * NN + wq * 512;

#pragma unroll
  for (int it = 0; it < 8; ++it) {
    const int j = it * 64 + lane;
    float a = ap[j];
    float sv = sp[j];
    bool nb = (a != 0.f);
    unsigned long long m = __ballot(nb);
    if (lane == 0) maskb[row * 32 + wq * 8 + it] = m;
    const int jg = wq * 512 + j;
    float es = nb ? __expf(sv) : 0.f;
    es_row[jg] = es;
    z2 += es;
    float4 eer4 = *(const float4*)(Eer_jh + jg * 4);
    float4 fer4 = *(const float4*)(Fer_jh + jg * 4);
    float ev[4] = {eer4.x, eer4.y, eer4.z, eer4.w};
    float fv[4] = {fer4.x, fer4.y, fer4.z, fer4.w};
#pragma unroll
    for (int h = 0; h < 4; ++h) {
      float p = eel[h] * ev[h];
      float q = fel[h] * fv[h];
      float E = fmaxf(p, q);
      z1[h] += nb ? E : 0.f;
    }
  }

#pragma unroll
  for (int m = 1; m < 64; m <<= 1) {
    z2 += __shfl_xor(z2, m);
#pragma unroll
    for (int h = 0; h < 4; ++h) z1[h] += __shfl_xor(z1[h], m);
  }

  if (lane == 0) {
    wr[wq][0] = z1[0]; wr[wq][1] = z1[1]; wr[wq][2] = z1[2]; wr[wq][3] = z1[3];
    wr[wq][4] = z2;
  }
  __syncthreads();
  if (tid < 4) {
    float sum = wr[0][tid] + wr[1][tid] + wr[2][tid] + wr[3][tid];
    rZ1[row * 4 + tid] = 1.f / sum;
  }
  const float rz2 = 1.f / (wr[0][4] + wr[1][4] + wr[2][4] + wr[3][4]);
  union { ushort u[8]; float4 f4; } pk;
#pragma unroll
  for (int e = 0; e < 8; ++e) {
    _Float16 hv = (_Float16)(es_row[tid * 8 + e] * rz2);
    union { _Float16 h; ushort u; } cv; cv.h = hv;
    pk.u[e] = cv.u;
  }
  *(float4*)(Esb + (size_t)row * NN + tid * 8) = pk.f4;
}

// -------- K4: coefficient + MFMA contraction. grid 2048 (16 jc) ------------
// wave = head h; lane: il = lane&15 (i-row), kg = lane>>4 (k-group). No dup.
__global__ __launch_bounds__(256, 8) void k_attn(
    const _Float16* __restrict__ Esb, const unsigned long long* __restrict__ maskb,
    const ushort* __restrict__ gTb,
    const float* __restrict__ Eel, const float* __restrict__ Fel,
    const float2* __restrict__ EF_hj, const float* __restrict__ rZ1,
    _Float16* __restrict__ U, float* __restrict__ Z3p) {
  const int tid = threadIdx.x;
  const int h = tid >> 6;
  const int lane = tid & 63;
  const int il = lane & 15;
  const int kg = lane >> 4;
  const int ib = blockIdx.x >> 4;
  const int jc = blockIdx.x & 15;
  const int i0 = ib * 16;
  const int jb0 = jc * 128;
  const int row = i0 + il;

  const float rz1 = rZ1[row * 4 + h];
  const float eelz = Eel[row * 4 + h] * rz1;
  const float felz = Fel[row * 4 + h] * rz1;

  const unsigned long long* mp = maskb + row * 32 + jc * 2;
  const unsigned long long m0 = mp[0];
  const unsigned long long m1 = mp[1];

  f32x4 acc[4];
#pragma unroll
  for (int nt = 0; nt < 4; ++nt) acc[nt] = (f32x4){0.f, 0.f, 0.f, 0.f};
  float z3 = 0.f;

  const _Float16* ep = Esb + (size_t)row * NN + jb0 + kg * 8;
  const float2* efp = EF_hj + h * NN + jb0 + kg * 8;
  const ushort* bp = gTb + (size_t)(jc * 16 + kg) * 2048 + (h * 64 + il) * 8;

#pragma unroll
  for (int ks = 0; ks < 4; ++ks) {
    const int o = ks * 32;
    // B loads first (independent; overlap with coefficient VALU)
    const ushort* bks = bp + (size_t)(ks * 4) * 2048;
    bf16x8 B0 = *(const bf16x8*)(bks);
    bf16x8 B1 = *(const bf16x8*)(bks + 128);
    bf16x8 B2 = *(const bf16x8*)(bks + 256);
    bf16x8 B3 = *(const bf16x8*)(bks + 384);

    unsigned long long w = (ks & 2) ? m1 : m0;
    unsigned byte_ = (unsigned)(w >> ((ks & 1) * 32 + kg * 8)) & 0xffu;

    union { float4 f4; _Float16 hx[8]; } eu;
    eu.f4 = *(const float4*)(ep + o);

    bf16x8 A;
#pragma unroll
    for (int gp = 0; gp < 2; ++gp) {
      float4 efa = *(const float4*)(efp + o + gp * 4);      // (eer,fer) x2
      float4 efb = *(const float4*)(efp + o + gp * 4 + 2);  // (eer,fer) x2
      float ev[4] = {efa.x, efa.z, efb.x, efb.z};
      float fv[4] = {efa.y, efa.w, efb.y, efb.w};
#pragma unroll
      for (int e = 0; e < 4; ++e) {
        const int ei = gp * 4 + e;
        bool nb = (byte_ >> ei) & 1u;
        float p = eelz * ev[e];
        float q = felz * fv[e];
        float tt = nb ? (fmaxf(p, q) + (float)eu.hx[ei]) : 0.f;
        float c = __expf(tt);
        z3 += c;
        A[ei] = (short)f2bf(c);
      }
    }

    acc[0] = __builtin_amdgcn_mfma_f32_16x16x32_bf16(A, B0, acc[0], 0, 0, 0);
    acc[1] = __builtin_amdgcn_mfma_f32_16x16x32_bf16(A, B1, acc[1], 0, 0, 0);
    acc[2] = __builtin_amdgcn_mfma_f32_16x16x32_bf16(A, B2, acc[2], 0, 0, 0);
    acc[3] = __builtin_amdgcn_mfma_f32_16x16x32_bf16(A, B3, acc[3], 0, 0, 0);
  }

  z3 += __shfl_xor(z3, 16);
  z3 += __shfl_xor(z3, 32);
  if (lane < 16)
    Z3p[jc * (NN * 4) + (i0 + lane) * 4 + h] = z3;

  _Float16* up = U + (size_t)jc * (NN * 256) + (size_t)i0 * 256 + h * 64 + il;
#pragma unroll
  for (int nt = 0; nt < 4; ++nt)
#pragma unroll
    for (int q = 0; q < 4; ++q)
      up[(size_t)(kg * 4 + q) * 256 + nt * 16] = (_Float16)acc[nt][q];
}

// -------- K5: combine 16 partials, divide by Z3. grid 2048 -----------------
__global__ __launch_bounds__(256) void k_final(
    const _Float16* __restrict__ U, const float* __restrict__ Z3p,
    float* __restrict__ out) {
  const int i = blockIdx.x;
  const int c = threadIdx.x;
  const int h = c >> 6;
  float u = 0.f, z = 0.f;
#pragma unroll
  for (int p = 0; p < 16; ++p) {
    u += (float)U[(size_t)p * (NN * 256) + (size_t)i * 256 + c];
    z += Z3p[p * (NN * 4) + i * 4 + h];
  }
  out[(size_t)i * 256 + c] = u / z;
}

extern "C" void kernel_launch(void* const* d_in, const int* in_sizes, int n_in,
                              void* d_out, int out_size, void* d_ws, size_t ws_size,
                              hipStream_t stream) {
  const float* hin = (const float*)d_in[0];
  const float* adj = (const float*)d_in[1];
  const float* s = (const float*)d_in[2];
  const float* W = (const float*)d_in[3];
  const float* aw = (const float*)d_in[4];
  float* out = (float*)d_out;

  // Workspace layout (f32 slots) — audited, non-overlapping:
  //  Eel     [      0,    8192)
  //  Fel     [   8192,   16384)
  //  Eer_jh  [  16384,   24576)
  //  Fer_jh  [  24576,   32768)
  //  EF_hj   [  32768,   49152)   8192 float2 (byte 131072 % 8 == 0)
  //  rZ1     [  49152,   57344)
  //  Z3p     [  57344,  188416)   16 * 8192
  //  maskb   [ 188416,  319488)   65536 u64 (byte 753664 % 8 == 0)
  //  wthi    [ 319488,  385024)   131072 ushort
  //  wtlo    [ 385024,  450560)   131072 ushort
  //  gTb     [ 450560,  712704)   524288 ushort
  //  Esb     [ 712704, 2809856)   2048*2048 f16
  //  U       [2809856, 4907008)   16*2048*256 f16
  float* ws = (float*)d_ws;
  float* Eel    = ws;
  float* Fel    = ws + 8192;
  float* Eer_jh = ws + 16384;
  float* Fer_jh = ws + 24576;
  float2* EF_hj = (float2*)(ws + 32768);
  float* rZ1    = ws + 49152;
  float* Z3p    = ws + 57344;
  unsigned long long* maskb = (unsigned long long*)(ws + 188416);
  ushort* wthi  = (ushort*)(ws + 319488);
  ushort* wtlo  = (ushort*)(ws + 385024);
  ushort* gTb   = (ushort*)(ws + 450560);
  _Float16* Esb = (_Float16*)(ws + 712704);
  _Float16* U   = (_Float16*)(ws + 2809856);

  k_wprep<<<32, 256, 0, stream>>>(W, wthi, wtlo);
  k_gemm<<<256, 256, 0, stream>>>(hin, wthi, wtlo, aw, gTb, Eel, Fel, Eer_jh, Fer_jh, EF_hj);
  k_rowz<<<2048, 256, 0, stream>>>(adj, s, Eel, Fel, Eer_jh, Fer_jh, rZ1, Esb, maskb);
  k_attn<<<2048, 256, 0, stream>>>(Esb, maskb, gTb, Eel, Fel, EF_hj, rZ1, U, Z3p);
  k_final<<<2048, 256, 0, stream>>>(U, Z3p, out);
}